// Round 10
// baseline (133.904 us; speedup 1.0000x reference)
//
#include <hip/hip_runtime.h>
#include <stdint.h>

constexpr int DOUT = 32;

// Fused single-kernel encoder: grid = B*16 blocks, block = (b, cg in 0..7, half).
// Each block: (1) stage its 4 W-columns in LDS, (2) interleaved loop
// {dot-product k-step for 512 ents x 4 ch} + {1 zero float4 store into its 4
// contiguous half-planes}, (3) __syncthreads (drains stores), (4) scatter its
// masked entities from registers via atomicAdd into the L2-hot planes.
// No cross-block dependencies; stores drain asynchronously under compute.
__global__ __launch_bounds__(256)
void k_fused(const float* __restrict__ emb,
             const float* __restrict__ weight,
             const float* __restrict__ bias,
             const int*   __restrict__ ex,
             const int*   __restrict__ ey,
             const int*   __restrict__ en,
             const int*   __restrict__ pW,
             float*       __restrict__ out,
             int N, int nent, int HW, int B, int DIN, int xcdmap)
{
    __shared__ float4 s_w4[256];      // s_w4[k] = {W[k][c0..c3]}  (4 KB)

    const int bid = blockIdx.x;
    const int tid = threadIdx.x;

    int b, cg, half;
    if (xcdmap) {                       // B%8==0: batch's 16 blocks share an XCD
        const int r = bid & 7, k = bid >> 3;
        b = r * (B >> 3) + (k >> 4);
        cg = (k >> 1) & 7;
        half = k & 1;
    } else {
        b = bid >> 4;
        cg = (bid >> 1) & 7;
        half = bid & 1;
    }

    // ---- W columns -> LDS
    for (int k = tid; k < DIN; k += 256)
        s_w4[k] = *(const float4*)&weight[(size_t)k * DOUT + cg * 4];
    __syncthreads();

    // ---- entity rows for this thread (slots tid, tid+256)
    const int eb = b * N;
    const int s0 = tid, s1 = tid + 256;
    const float* row0 = emb + (size_t)(eb + (s0 < N ? s0 : 0)) * DIN;
    const float* row1 = emb + (size_t)(eb + (s1 < N ? s1 : 0)) * DIN;

    // ---- zero-store bookkeeping: 4 half-planes, contiguous chunks of n4h f4
    const int h0  = half * (HW >> 1);
    const int n4h = HW >> 3;                       // f4 per half-plane
    const size_t pbase = (size_t)(b * DOUT + cg * 4) * HW + h0;
    int zc = 0, zo = tid;
    while (zo >= n4h) { zo -= n4h; ++zc; }
    const float4 z4 = make_float4(0.f, 0.f, 0.f, 0.f);

    float a00=0.f,a01=0.f,a02=0.f,a03=0.f;
    float a10=0.f,a11=0.f,a12=0.f,a13=0.f;

    const int K4 = DIN >> 2;
    #pragma unroll 2
    for (int k4 = 0; k4 < K4; ++k4) {
        const float4 e0 = *(const float4*)(row0 + (k4 << 2));
        const float4 e1 = *(const float4*)(row1 + (k4 << 2));

        // one interleaved zero store (younger than the loads -> doesn't stall fma)
        if (zc < 4) {
            *(float4*)(out + pbase + (size_t)zc * HW + ((size_t)zo << 2)) = z4;
            zo += 256;
            if (zo >= n4h) { zo -= n4h; ++zc; }
        }

        const float4 w0 = s_w4[(k4 << 2) + 0];
        const float4 w1 = s_w4[(k4 << 2) + 1];
        const float4 w2 = s_w4[(k4 << 2) + 2];
        const float4 w3 = s_w4[(k4 << 2) + 3];
        a00 += e0.x*w0.x + e0.y*w1.x + e0.z*w2.x + e0.w*w3.x;
        a01 += e0.x*w0.y + e0.y*w1.y + e0.z*w2.y + e0.w*w3.y;
        a02 += e0.x*w0.z + e0.y*w1.z + e0.z*w2.z + e0.w*w3.z;
        a03 += e0.x*w0.w + e0.y*w1.w + e0.z*w2.w + e0.w*w3.w;
        a10 += e1.x*w0.x + e1.y*w1.x + e1.z*w2.x + e1.w*w3.x;
        a11 += e1.x*w0.y + e1.y*w1.y + e1.z*w2.y + e1.w*w3.y;
        a12 += e1.x*w0.z + e1.y*w1.z + e1.z*w2.z + e1.w*w3.z;
        a13 += e1.x*w0.w + e1.y*w1.w + e1.z*w2.w + e1.w*w3.w;
    }
    // drain any remaining zero stores (HW-general; no-op for HW=25600)
    while (zc < 4) {
        *(float4*)(out + pbase + (size_t)zc * HW + ((size_t)zo << 2)) = z4;
        zo += 256;
        if (zo >= n4h) { zo -= n4h; ++zc; }
    }

    __syncthreads();   // compiler-inserted vmcnt(0): all zeros visible before atomics

    // ---- scatter from registers (mask + own-half check), L2-hot atomics
    const int cnt = min(en[b], N);
    const int W = *pW;
    const int hlen = HW - (HW >> 1) * half - h0 + (half ? 0 : 0); // = HW>>1 (HW even)
    const int hend = h0 + (HW >> 1);
    const float4 bv = *(const float4*)&bias[cg * 4];
    float* dst0 = out + (size_t)(b * DOUT + cg * 4) * HW;

    if (s0 < cnt) {
        const int ent = eb + s0;
        const int hw = ey[ent] * W + ex[ent];
        if (hw >= h0 && hw < hend) {
            const float v0 = fmaxf(a00 + bv.x, 0.f);
            const float v1 = fmaxf(a01 + bv.y, 0.f);
            const float v2 = fmaxf(a02 + bv.z, 0.f);
            const float v3 = fmaxf(a03 + bv.w, 0.f);
            if (v0 != 0.f) atomicAdd(dst0 + hw, v0);
            if (v1 != 0.f) atomicAdd(dst0 + HW + hw, v1);
            if (v2 != 0.f) atomicAdd(dst0 + 2 * (size_t)HW + hw, v2);
            if (v3 != 0.f) atomicAdd(dst0 + 3 * (size_t)HW + hw, v3);
        }
    }
    if (s1 < cnt) {
        const int ent = eb + s1;
        const int hw = ey[ent] * W + ex[ent];
        if (hw >= h0 && hw < hend) {
            const float v0 = fmaxf(a10 + bv.x, 0.f);
            const float v1 = fmaxf(a11 + bv.y, 0.f);
            const float v2 = fmaxf(a12 + bv.z, 0.f);
            const float v3 = fmaxf(a13 + bv.w, 0.f);
            if (v0 != 0.f) atomicAdd(dst0 + hw, v0);
            if (v1 != 0.f) atomicAdd(dst0 + HW + hw, v1);
            if (v2 != 0.f) atomicAdd(dst0 + 2 * (size_t)HW + hw, v2);
            if (v3 != 0.f) atomicAdd(dst0 + 3 * (size_t)HW + hw, v3);
        }
    }
}

// ---------------- fallback: memset + R4's proven fused kernel ----------------
constexpr int FDIN = 256;
constexpr int FET = 64, FKT = 64, FEP = FKT + 4;
__global__ __launch_bounds__(256)
void enc_fallback(const float* __restrict__ emb, const float* __restrict__ weight,
                  const float* __restrict__ bias, const int* __restrict__ ex,
                  const int* __restrict__ ey, const int* __restrict__ en,
                  const int* __restrict__ pW, float* __restrict__ out,
                  int N, int nent, int HW)
{
    __shared__ float s_emb[FET][FEP];
    __shared__ float s_w[FKT * DOUT];
    const int tid = threadIdx.x;
    const int og = tid & 7, eg = tid >> 3;
    const int eb = blockIdx.x * FET;
    float4 pe[4]; float4 pw[2];
    #pragma unroll
    for (int r = 0; r < 4; ++r) {
        int f = (r << 8) + tid, rw = f >> 4, col = (f & 15) << 2;
        int e = eb + rw; if (e >= nent) e = nent - 1;
        pe[r] = *(const float4*)&emb[(size_t)e * FDIN + col];
    }
    #pragma unroll
    for (int r = 0; r < 2; ++r) pw[r] = *(const float4*)&weight[(size_t)(((r << 8) + tid) << 2)];
    float acc[2][4] = {{0,0,0,0},{0,0,0,0}};
    for (int t = 0; t < 4; ++t) {
        #pragma unroll
        for (int r = 0; r < 4; ++r) {
            int f = (r << 8) + tid;
            *(float4*)&s_emb[f >> 4][(f & 15) << 2] = pe[r];
        }
        #pragma unroll
        for (int r = 0; r < 2; ++r) *(float4*)&s_w[((r << 8) + tid) << 2] = pw[r];
        __syncthreads();
        if (t < 3) {
            const int kt = (t + 1) * FKT;
            #pragma unroll
            for (int r = 0; r < 4; ++r) {
                int f = (r << 8) + tid, rw = f >> 4, col = (f & 15) << 2;
                int e = eb + rw; if (e >= nent) e = nent - 1;
                pe[r] = *(const float4*)&emb[(size_t)e * FDIN + kt + col];
            }
            #pragma unroll
            for (int r = 0; r < 2; ++r)
                pw[r] = *(const float4*)&weight[(size_t)kt * DOUT + (((r << 8) + tid) << 2)];
        }
        #pragma unroll
        for (int k = 0; k < FKT; k += 4) {
            float4 e0 = *(const float4*)&s_emb[eg][k];
            float4 e1 = *(const float4*)&s_emb[eg + 32][k];
            float4 w0 = *(const float4*)&s_w[(k + 0) * DOUT + og * 4];
            float4 w1 = *(const float4*)&s_w[(k + 1) * DOUT + og * 4];
            float4 w2 = *(const float4*)&s_w[(k + 2) * DOUT + og * 4];
            float4 w3 = *(const float4*)&s_w[(k + 3) * DOUT + og * 4];
            acc[0][0] += e0.x*w0.x + e0.y*w1.x + e0.z*w2.x + e0.w*w3.x;
            acc[0][1] += e0.x*w0.y + e0.y*w1.y + e0.z*w2.y + e0.w*w3.y;
            acc[0][2] += e0.x*w0.z + e0.y*w1.z + e0.z*w2.z + e0.w*w3.z;
            acc[0][3] += e0.x*w0.w + e0.y*w1.w + e0.z*w2.w + e0.w*w3.w;
            acc[1][0] += e1.x*w0.x + e1.y*w1.x + e1.z*w2.x + e1.w*w3.x;
            acc[1][1] += e1.x*w0.y + e1.y*w1.y + e1.z*w2.y + e1.w*w3.y;
            acc[1][2] += e1.x*w0.z + e1.y*w1.z + e1.z*w2.z + e1.w*w3.z;
            acc[1][3] += e1.x*w0.w + e1.y*w1.w + e1.z*w2.w + e1.w*w3.w;
        }
        __syncthreads();
    }
    const int W = *pW;
    const float4 bv = *(const float4*)&bias[og * 4];
    #pragma unroll
    for (int i = 0; i < 2; ++i) {
        int ent = eb + eg + i * 32;
        if (ent >= nent) continue;
        int b = ent / N, n = ent - b * N;
        if (n >= en[b]) continue;
        float* dst = out + ((size_t)b * DOUT + og * 4) * (size_t)HW
                         + (size_t)ey[ent] * W + ex[ent];
        float v0 = fmaxf(acc[i][0] + bv.x, 0.f);
        float v1 = fmaxf(acc[i][1] + bv.y, 0.f);
        float v2 = fmaxf(acc[i][2] + bv.z, 0.f);
        float v3 = fmaxf(acc[i][3] + bv.w, 0.f);
        if (v0 != 0.f) atomicAdd(dst + 0 * (size_t)HW, v0);
        if (v1 != 0.f) atomicAdd(dst + 1 * (size_t)HW, v1);
        if (v2 != 0.f) atomicAdd(dst + 2 * (size_t)HW, v2);
        if (v3 != 0.f) atomicAdd(dst + 3 * (size_t)HW, v3);
    }
}

extern "C" void kernel_launch(void* const* d_in, const int* in_sizes, int n_in,
                              void* d_out, int out_size, void* d_ws, size_t ws_size,
                              hipStream_t stream) {
    const float* emb    = (const float*)d_in[0];
    const float* weight = (const float*)d_in[1];
    const float* bias   = (const float*)d_in[2];
    const int*   ex     = (const int*)d_in[3];
    const int*   ey     = (const int*)d_in[4];
    const int*   en     = (const int*)d_in[5];
    const int*   pW     = (const int*)d_in[7];
    float*       out    = (float*)d_out;

    const int nent = in_sizes[3];                    // B*N
    const int B    = in_sizes[5];
    const int N    = nent / B;
    const int DIN  = in_sizes[0] / nent;             // 256
    const int HW   = (int)((size_t)out_size / ((size_t)B * DOUT));

    const bool fused_ok = (N >= 1) && (N <= 512) && (B * N == nent) &&
                          (DIN == 256) && (in_sizes[2] == DOUT) &&
                          (HW % 8 == 0) && (HW >= 8);

    if (fused_ok) {
        const int xcdmap = (B % 8 == 0) ? 1 : 0;
        k_fused<<<B * 16, 256, 0, stream>>>(emb, weight, bias, ex, ey, en, pW,
                                            out, N, nent, HW, B, DIN, xcdmap);
    } else {
        (void)hipMemsetAsync(d_out, 0, (size_t)out_size * sizeof(float), stream);
        const int blocks = (nent + FET - 1) / FET;
        enc_fallback<<<blocks, 256, 0, stream>>>(emb, weight, bias, ex, ey, en, pW,
                                                 out, N, nent, HW);
    }
}